// Round 8
// baseline (288.436 us; speedup 1.0000x reference)
//
#include <hip/hip_runtime.h>
#include <math.h>

// Problem constants (fixed by reference)
constexpr int BB = 4;
constexpr int TT = 2048;
constexpr int CC = 1024;
constexpr int NHH = 16;
constexpr int HDD = 64;    // head dim
constexpr int C3 = 3 * CC; // 3072

typedef __bf16 bf16x8 __attribute__((ext_vector_type(8)));
typedef __bf16 bf16x4 __attribute__((ext_vector_type(4)));
typedef float  f32x4  __attribute__((ext_vector_type(4)));

__device__ __forceinline__ unsigned short f2bf(float x) {
    union { float f; unsigned u; } v; v.f = x;
    unsigned r = v.u + 0x7fffu + ((v.u >> 16) & 1u);  // RNE
    return (unsigned short)(r >> 16);
}

#define AS1(p) ((const __attribute__((address_space(1))) void*)(p))
#define AS3(p) ((__attribute__((address_space(3))) void*)(p))

constexpr float SM2 = 17.312340490667561f;    // 12 * log2(e)

// ---------------------------------------------------------------------------
// prep: (a) x fp32->bf16 cast, (b) W_qkv transpose+cast, (c) W_out
// transpose+cast, (d) kbias = (mask-1)*1e38 - SM2 (fp32) — block-range dispatch.
// ---------------------------------------------------------------------------
constexpr int CAST_BLOCKS = (BB * TT * CC / 4) / 256;          // 8192
constexpr int TQKV_BLOCKS = (C3 / 64) * (CC / 64);             // 768
constexpr int TOUT_BLOCKS = (CC / 64) * (CC / 64);             // 256
constexpr int KB_BLOCKS   = (BB * TT) / 256;                   // 32

__global__ __launch_bounds__(256) void prep(
    const float* __restrict__ x,
    const float* __restrict__ Wqkv,
    const float* __restrict__ Wout,
    const float* __restrict__ amask,
    unsigned short* __restrict__ xb,
    unsigned short* __restrict__ Wqkvt,
    unsigned short* __restrict__ Woutt,
    float* __restrict__ kbias)
{
    __shared__ float tile[64][65];
    const int bid = blockIdx.x;
    const int t = threadIdx.x;

    if (bid < CAST_BLOCKS) {
        const int i = bid * 256 + t;
        float4 v = ((const float4*)x)[i];
        ushort4 o;
        o.x = f2bf(v.x); o.y = f2bf(v.y); o.z = f2bf(v.z); o.w = f2bf(v.w);
        ((ushort4*)xb)[i] = o;
        return;
    }
    if (bid >= CAST_BLOCKS + TQKV_BLOCKS + TOUT_BLOCKS) {
        const int i = (bid - CAST_BLOCKS - TQKV_BLOCKS - TOUT_BLOCKS) * 256 + t;
        kbias[i] = (amask[i] - 1.0f) * 1.0e38f - SM2;
        return;
    }

    const float* src; unsigned short* dst; int R, Cn, r0, c0;
    if (bid < CAST_BLOCKS + TQKV_BLOCKS) {
        const int tb = bid - CAST_BLOCKS;
        src = Wqkv; dst = Wqkvt; R = CC; Cn = C3;
        c0 = (tb % (C3 / 64)) * 64; r0 = (tb / (C3 / 64)) * 64;
    } else {
        const int tb = bid - CAST_BLOCKS - TQKV_BLOCKS;
        src = Wout; dst = Woutt; R = CC; Cn = CC;
        c0 = (tb % (CC / 64)) * 64; r0 = (tb / (CC / 64)) * 64;
    }

    const int lr = t >> 4, lc = (t & 15) * 4;
    #pragma unroll
    for (int s = 0; s < 4; ++s) {
        float4 v = *(const float4*)&src[(size_t)(r0 + lr + s * 16) * Cn + c0 + lc];
        tile[lr + s * 16][lc + 0] = v.x;
        tile[lr + s * 16][lc + 1] = v.y;
        tile[lr + s * 16][lc + 2] = v.z;
        tile[lr + s * 16][lc + 3] = v.w;
    }
    __syncthreads();
    const int oi = t >> 2, oc = (t & 3) * 16;
    unsigned short buf[16];
    #pragma unroll
    for (int u = 0; u < 16; ++u)
        buf[u] = f2bf(tile[oc + u][oi]);
    unsigned short* d = &dst[(size_t)(c0 + oi) * R + r0 + oc];
    *(uint4*)(d + 0) = *(uint4*)&buf[0];
    *(uint4*)(d + 8) = *(uint4*)&buf[8];
}

// ---------------------------------------------------------------------------
// bf16 MFMA GEMM (R5-verified 128x128 structure, both operands via LDS):
// BK=64, XOR-swizzled global_load_lds, counted-vmcnt double-buffer
// (DMA kt+2 after barrier-1, vmcnt(8) across barrier-2), 64KB LDS ->
// 2 blocks/CU. XCD-grouped bijective decode. VSPLIT: Q->Qp scaled,
// K->Kp packed, V->Vtp transposed. Non-VSPLIT: fp32 Out + bias.
// This structure is at ~92% of its LDS-pipe roofline; R4/R6/R7 proved
// tile-size moves that drop waves/CU regress. Do not touch.
// ---------------------------------------------------------------------------
template<bool VSPLIT>
__global__ __launch_bounds__(256, 2) void gemm_bt_mfma(
    const unsigned short* __restrict__ A,   // [M][K]
    const unsigned short* __restrict__ Bt,  // [N][K]
    const float* __restrict__ bias,
    float* __restrict__ OutF,
    unsigned short* __restrict__ Qp,
    unsigned short* __restrict__ Kp,
    unsigned short* __restrict__ Vtp,
    int M, int N, int K, float qscale)
{
    __shared__ alignas(16) unsigned short As[2][128 * 64];  // 32 KB
    __shared__ alignas(16) unsigned short Bs[2][128 * 64];  // 32 KB

    const int tid  = threadIdx.x;
    const int w    = tid >> 6;
    const int lane = tid & 63;
    const int quad = lane >> 4;
    const int col  = lane & 15;

    const int nX  = gridDim.x;
    const int lin = blockIdx.y * nX + blockIdx.x;
    const int pos = lin >> 3;
    const int mt  = ((lin & 7) << 3) | (pos & 7);
    const int nt  = pos >> 3;
    const int m0 = mt * 128, n0 = nt * 128;
    const int wr = w >> 1, wc = w & 1;

    f32x4 acc[4][4];
    #pragma unroll
    for (int i = 0; i < 4; ++i)
        #pragma unroll
        for (int j = 0; j < 4; ++j)
            #pragma unroll
            for (int r = 0; r < 4; ++r)
                acc[i][j][r] = 0.0f;

    const int srow = tid >> 3;   // 0..31
    const int spos = tid & 7;
    char* AsB = (char*)&As[0][0];
    char* BsB = (char*)&Bs[0][0];

    const int nk = K >> 6;

    auto DMA = [&](int kt, int buf) {
        const int k0 = kt << 6;
        #pragma unroll
        for (int i = 0; i < 4; ++i) {
            const int row = srow + 32 * i;
            const int sc = spos ^ (row & 7);
            __builtin_amdgcn_global_load_lds(
                AS1(A + (size_t)(m0 + row) * K + k0 + sc * 8),
                AS3(AsB + buf * 16384 + i * 4096 + w * 1024), 16, 0, 0);
            __builtin_amdgcn_global_load_lds(
                AS1(Bt + (size_t)(n0 + row) * K + k0 + sc * 8),
                AS3(BsB + buf * 16384 + i * 4096 + w * 1024), 16, 0, 0);
        }
    };

    DMA(0, 0);
    DMA(1, 1);
    asm volatile("s_waitcnt vmcnt(8)" ::: "memory");   // tile 0 landed
    __builtin_amdgcn_s_barrier();

    for (int kt = 0; kt < nk; ++kt) {
        const int cur = kt & 1;
        const unsigned short* as = &As[cur][0];
        const unsigned short* bs = &Bs[cur][0];

        #pragma unroll
        for (int ks = 0; ks < 2; ++ks) {
            bf16x8 af[4], bf[4];
            #pragma unroll
            for (int i = 0; i < 4; ++i) {
                const int ra = wr * 64 + i * 16 + col;
                const int pa = ((quad + ks * 4) ^ (ra & 7)) * 8;
                af[i] = *(const bf16x8*)&as[ra * 64 + pa];
                const int rb = wc * 64 + i * 16 + col;
                const int pb = ((quad + ks * 4) ^ (rb & 7)) * 8;
                bf[i] = *(const bf16x8*)&bs[rb * 64 + pb];
            }
            #pragma unroll
            for (int i = 0; i < 4; ++i)
                #pragma unroll
                for (int j = 0; j < 4; ++j)
                    acc[i][j] = __builtin_amdgcn_mfma_f32_16x16x32_bf16(af[i], bf[j], acc[i][j], 0, 0, 0);
        }

        __builtin_amdgcn_s_barrier();
        if (kt + 2 < nk) {
            DMA(kt + 2, cur);
            asm volatile("s_waitcnt vmcnt(8)" ::: "memory");
        } else {
            asm volatile("s_waitcnt vmcnt(0)" ::: "memory");
        }
        __builtin_amdgcn_s_barrier();
    }

    if (VSPLIT) {
        if (n0 < CC) {
            #pragma unroll
            for (int i = 0; i < 4; ++i)
                #pragma unroll
                for (int r = 0; r < 4; ++r) {
                    const int m = m0 + wr * 64 + i * 16 + quad * 4 + r;
                    #pragma unroll
                    for (int j = 0; j < 4; ++j) {
                        const int n = n0 + wc * 64 + j * 16 + col;
                        Qp[(size_t)m * CC + n] = f2bf((acc[i][j][r] + bias[n]) * qscale);
                    }
                }
        } else if (n0 < 2 * CC) {
            #pragma unroll
            for (int i = 0; i < 4; ++i) {
                const int mb   = m0 + wr * 64 + i * 16 + quad * 4;  // + r
                const int bidx = mb >> 11;
                const int tloc = mb & 2047;
                #pragma unroll
                for (int j = 0; j < 4; ++j) {
                    const int n  = n0 + wc * 64 + j * 16 + col;
                    const int hh = (n - CC) >> 6;
                    const int dd = (n - CC) & 63;
                    #pragma unroll
                    for (int r = 0; r < 4; ++r)
                        Kp[(((size_t)bidx * NHH + hh) * TT + tloc + r) * HDD + dd] =
                            f2bf(acc[i][j][r] + bias[n]);
                }
            }
        } else {
            #pragma unroll
            for (int i = 0; i < 4; ++i) {
                const int mb   = m0 + wr * 64 + i * 16 + quad * 4;  // + r
                const int bidx = mb >> 11;
                const int tloc = mb & 2047;
                const int ktile = tloc >> 6, tc = tloc & 63;
                #pragma unroll
                for (int j = 0; j < 4; ++j) {
                    const int n  = n0 + wc * 64 + j * 16 + col;
                    const int hh = (n - 2 * CC) >> 6;
                    const int dd = (n - 2 * CC) & 63;
                    unsigned short pk[4];
                    #pragma unroll
                    for (int r = 0; r < 4; ++r)
                        pk[r] = f2bf(acc[i][j][r] + bias[n]);
                    *(uint2*)&Vtp[((((size_t)bidx * NHH + hh) * 32 + ktile) * HDD + dd) * 64 + tc] =
                        *(const uint2*)pk;
                }
            }
        }
    } else {
        #pragma unroll
        for (int i = 0; i < 4; ++i)
            #pragma unroll
            for (int r = 0; r < 4; ++r) {
                const int m = m0 + wr * 64 + i * 16 + quad * 4 + r;
                #pragma unroll
                for (int j = 0; j < 4; ++j) {
                    const int n = n0 + wc * 64 + j * 16 + col;
                    OutF[(size_t)m * N + n] = acc[i][j][r] + bias[n];
                }
            }
    }
}

// ---------------------------------------------------------------------------
// MFMA flash attention v12: 256-q tile per block (8 waves x 32 q-rows,
// 512 threads) — v11's 60us was overhead-bound (3.4 TFLOP at ~57 TF,
// 17408 block-tile-steps each paying DMA+2 barriers+softmax for 64 MFMAs).
// Doubling q-rows per K/V tile halves tile-steps (9216) and K/V L2 reads.
// Per-wave inner code IDENTICAL to v11 (swapped QK^T, ds_write_b64 P,
// kbias C-init, scalar l). Staging at 512 threads = 1 issue per operand
// (srow = tid>>3 in 0..63) -> vmcnt(6) steady (2 DMA + 4 kb in flight).
// Grid 512 = 64 bh x 8 q-tiles, qb DESCENDING so greedy scheduler pairs
// (7,0),(6,1),(5,2),(4,3) -> ~36 uniform steps/CU at 2 blocks/CU.
// LDS 69.6KB -> 2 blocks/CU = 16 waves/CU. Causal branch hoisted
// wave-uniform (skips 32 cndmask on non-edge tiles).
// ---------------------------------------------------------------------------
constexpr int PP = 72;           // Ps row stride (bf16); 144B: 16B-aligned rows

__global__ __launch_bounds__(512, 4) void attn_mfma(
    const unsigned short* __restrict__ Qp,
    const unsigned short* __restrict__ Kp,
    const unsigned short* __restrict__ Vtp,
    const float* __restrict__ kbias,
    unsigned short* __restrict__ WV)
{
    __shared__ alignas(16) unsigned short Ks [2][64 * 64];  // 16 KB
    __shared__ alignas(16) unsigned short Vts[2][64 * 64];  // 16 KB
    __shared__ alignas(16) __bf16        Ps[8][32 * PP];    // 36.9 KB

    const int tid  = threadIdx.x;
    const int w    = tid >> 6;       // 0..7
    const int lane = tid & 63;
    const int quad = lane >> 4;
    const int col  = lane & 15;

    // grid decode: 512 blocks; xcd = gi&7 owns bh band [8x, 8x+8);
    // qb = 7 - (j>>3) descends with dispatch order (big blocks first).
    const int gi = blockIdx.x;
    const int j  = gi >> 3;
    const int bh = ((gi & 7) << 3) | (j & 7);
    const int qb = 7 - (j >> 3);                 // 0..7 (q-tile of 256 rows)
    const int b = bh >> 4, h = bh & 15;

    const unsigned short* Qg = Qp + (size_t)b * TT * CC + (size_t)h * HDD;
    const unsigned short* Kg = Kp + (size_t)bh * TT * HDD;
    const unsigned short* Vg = Vtp + (size_t)bh * 32 * HDD * 64;
    const float* kb_g = kbias + b * TT;

    // staging map (512 threads): row = tid>>3 in 0..63, chunk = tid&7;
    // fetched chunk = (tid&7) ^ (row&7) so frag reads de-swizzle clean.
    const int srow = tid >> 3;
    const int sch  = (tid & 7) ^ (srow & 7);
    char* KsB  = (char*)&Ks[0][0];
    char* VtsB = (char*)&Vts[0][0];

    const int qw = qb * 256 + w * 32;   // wave's first q row (32 rows)
    const int ntiles = 4 * qb + 4;

    // Q fragments direct from global; B-frags for S^T = mfma(K,Q)
    bf16x8 qfa0 = *(const bf16x8*)(Qg + (size_t)(qw + col) * CC + quad * 8);
    bf16x8 qfa1 = *(const bf16x8*)(Qg + (size_t)(qw + col) * CC + 32 + quad * 8);
    bf16x8 qfb0 = *(const bf16x8*)(Qg + (size_t)(qw + 16 + col) * CC + quad * 8);
    bf16x8 qfb1 = *(const bf16x8*)(Qg + (size_t)(qw + 16 + col) * CC + 32 + quad * 8);

    f32x4 o[2][4];
    float l[2] = {0.0f, 0.0f};
    #pragma unroll
    for (int hh = 0; hh < 2; ++hh)
        #pragma unroll
        for (int t = 0; t < 4; ++t)
            #pragma unroll
            for (int r = 0; r < 4; ++r) o[hh][t][r] = 0.0f;

    // DMA one 64-key tile (K + Vt, 8KB each = 1 issue each at 512 thr)
    auto DMA = [&](int tile, int buf) {
        __builtin_amdgcn_global_load_lds(
            AS1(Kg + (size_t)(tile * 64 + srow) * HDD + sch * 8),
            AS3(KsB + buf * 8192 + w * 1024), 16, 0, 0);
        __builtin_amdgcn_global_load_lds(
            AS1(Vg + ((size_t)tile * 64 + srow) * 64 + sch * 8),
            AS3(VtsB + buf * 8192 + w * 1024), 16, 0, 0);
    };

    // prologue: tiles 0 and 1 in flight; kb for tiles 0 and 1
    f32x4 kbc[4], kbn[4];
    DMA(0, 0);
    #pragma unroll
    for (int t = 0; t < 4; ++t)
        kbc[t] = *(const f32x4*)&kb_g[t * 16 + quad * 4];
    DMA(1, 1);
    #pragma unroll
    for (int t = 0; t < 4; ++t)
        kbn[t] = *(const f32x4*)&kb_g[64 + t * 16 + quad * 4];
    asm volatile("s_waitcnt vmcnt(6)" ::: "memory");   // tile 0 + kb0 landed
    __builtin_amdgcn_s_barrier();

    for (int it = 0; it < ntiles; ++it) {
        const int kt  = it << 6;
        const int cur = it & 1;

        if (kt <= qw + 31) {  // wave active for this key-tile
            const unsigned short* ksb = &Ks[cur][0];
            const unsigned short* vsb = &Vts[cur][0];

            // --- S^T = K Q^T + kb: lane holds S[q=..+col][key=kt+t*16+quad*4+r]
            f32x4 s[2][4];
            #pragma unroll
            for (int t = 0; t < 4; ++t) {
                const int row = t * 16 + col;
                const int c0 = (quad ^ (row & 7)) * 8;
                const int c1 = ((quad + 4) ^ (row & 7)) * 8;
                bf16x8 k0 = *(const bf16x8*)&ksb[row * 64 + c0];
                bf16x8 k1 = *(const bf16x8*)&ksb[row * 64 + c1];
                f32x4 za = __builtin_amdgcn_mfma_f32_16x16x32_bf16(k0, qfa0, kbc[t], 0, 0, 0);
                za = __builtin_amdgcn_mfma_f32_16x16x32_bf16(k1, qfa1, za, 0, 0, 0);
                s[0][t] = za;
                f32x4 zb = __builtin_amdgcn_mfma_f32_16x16x32_bf16(k0, qfb0, kbc[t], 0, 0, 0);
                zb = __builtin_amdgcn_mfma_f32_16x16x32_bf16(k1, qfb1, zb, 0, 0, 0);
                s[1][t] = zb;
            }

            // --- p = 2^s; causal zero only on wave-edge tiles (uniform) ---
            if (kt + 64 > qw) {
                #pragma unroll
                for (int hh = 0; hh < 2; ++hh) {
                    const int q = qw + hh * 16 + col;
                    #pragma unroll
                    for (int t = 0; t < 4; ++t) {
                        float pv[4];
                        #pragma unroll
                        for (int r = 0; r < 4; ++r) {
                            const int key = kt + t * 16 + quad * 4 + r;
                            float p = __builtin_amdgcn_exp2f(s[hh][t][r]);
                            if (key > q) p = 0.0f;
                            l[hh] += p;
                            pv[r] = p;
                        }
                        bf16x4 pk4 = { (__bf16)pv[0], (__bf16)pv[1],
                                       (__bf16)pv[2], (__bf16)pv[3] };
                        *(bf16x4*)&Ps[w][(hh * 16 + col) * PP + t * 16 + quad * 4] = pk4;
                    }
                }
            } else {
                #pragma unroll
                for (int hh = 0; hh < 2; ++hh) {
                    #pragma unroll
                    for (int t = 0; t < 4; ++t) {
                        float pv[4];
                        #pragma unroll
                        for (int r = 0; r < 4; ++r) {
                            float p = __builtin_amdgcn_exp2f(s[hh][t][r]);
                            l[hh] += p;
                            pv[r] = p;
                        }
                        bf16x4 pk4 = { (__bf16)pv[0], (__bf16)pv[1],
                                       (__bf16)pv[2], (__bf16)pv[3] };
                        *(bf16x4*)&Ps[w][(hh * 16 + col) * PP + t * 16 + quad * 4] = pk4;
                    }
                }
            }

            // --- PV: O += P V; P read back as A-frag (2 b128 per half) ---
            bf16x8 pa0 = *(const bf16x8*)&Ps[w][col * PP + quad * 8];
            bf16x8 pa1 = *(const bf16x8*)&Ps[w][col * PP + 32 + quad * 8];
            bf16x8 pb0 = *(const bf16x8*)&Ps[w][(16 + col) * PP + quad * 8];
            bf16x8 pb1 = *(const bf16x8*)&Ps[w][(16 + col) * PP + 32 + quad * 8];
            #pragma unroll
            for (int t = 0; t < 4; ++t) {
                const int row = t * 16 + col;
                const int c0 = (quad ^ (row & 7)) * 8;
                const int c1 = ((quad + 4) ^ (row & 7)) * 8;
                bf16x8 v0 = *(const bf16x8*)&vsb[row * 64 + c0];
                bf16x8 v1 = *(const bf16x8*)&vsb[row * 64 + c1];
                o[0][t] = __builtin_amdgcn_mfma_f32_16x16x32_bf16(pa0, v0, o[0][t], 0, 0, 0);
                o[0][t] = __builtin_amdgcn_mfma_f32_16x16x32_bf16(pa1, v1, o[0][t], 0, 0, 0);
                o[1][t] = __builtin_amdgcn_mfma_f32_16x16x32_bf16(pb0, v0, o[1][t], 0, 0, 0);
                o[1][t] = __builtin_amdgcn_mfma_f32_16x16x32_bf16(pb1, v1, o[1][t], 0, 0, 0);
            }
        }

        // barrier 1: all waves done READING buf[cur] -> safe to overwrite
        __builtin_amdgcn_s_barrier();

        #pragma unroll
        for (int t = 0; t < 4; ++t) kbc[t] = kbn[t];

        if (it + 2 < ntiles) {
            DMA(it + 2, cur);
            #pragma unroll
            for (int t = 0; t < 4; ++t)
                kbn[t] = *(const f32x4*)&kb_g[(it + 2) * 64 + t * 16 + quad * 4];
            // tile it+1 (+kb) landed; tile it+2's 2 DMA + 4 kb in flight
            asm volatile("s_waitcnt vmcnt(6)" ::: "memory");
        } else {
            asm volatile("s_waitcnt vmcnt(0)" ::: "memory");
        }
        // barrier 2: buf[(it+1)&1] published to all waves
        __builtin_amdgcn_s_barrier();
    }

    // --- l: reduce across quads (lanes sharing col), broadcast per out-row ---
    #pragma unroll
    for (int hh = 0; hh < 2; ++hh) {
        l[hh] += __shfl_xor(l[hh], 16);
        l[hh] += __shfl_xor(l[hh], 32);
    }
    #pragma unroll
    for (int hh = 0; hh < 2; ++hh) {
        #pragma unroll
        for (int r = 0; r < 4; ++r) {
            const float Lr = __shfl(l[hh], (lane & 48) | (quad * 4 + r));
            const float inv = 1.0f / Lr;
            const int q = qw + hh * 16 + quad * 4 + r;
            unsigned short* dst = WV + ((size_t)b * TT + q) * CC + (size_t)h * HDD;
            #pragma unroll
            for (int t = 0; t < 4; ++t)
                dst[t * 16 + col] = f2bf(o[hh][t][r] * inv);
        }
    }
}

// ---------------------------------------------------------------------------
// Launch
// ---------------------------------------------------------------------------
extern "C" void kernel_launch(void* const* d_in, const int* in_sizes, int n_in,
                              void* d_out, int out_size, void* d_ws, size_t ws_size,
                              hipStream_t stream) {
    const float* x     = (const float*)d_in[0]; // (B,T,C)
    const float* amask = (const float*)d_in[1]; // (B,T)
    const float* Wqkv  = (const float*)d_in[2]; // (C,3C)
    const float* bqkv  = (const float*)d_in[3]; // (3C)
    const float* Wout  = (const float*)d_in[4]; // (C,C)
    const float* bout  = (const float*)d_in[5]; // (C)
    float* out = (float*)d_out;                 // (B,T,C)

    const int M = BB * TT; // 8192

    // Workspace: xb 16M | Wqkvt 6M | Woutt 2M | Qp 16M | Kp 16M | Vtp 16M |
    //            wvb 16M | kbias 32K  (total ~88 MB)
    unsigned short* xb    = (unsigned short*)d_ws;
    unsigned short* Wqkvt = xb    + (size_t)M * CC;
    unsigned short* Woutt = Wqkvt + (size_t)C3 * CC;
    unsigned short* Qp    = Woutt + (size_t)CC * CC;
    unsigned short* Kp    = Qp    + (size_t)M * CC;
    unsigned short* Vtp   = Kp    + (size_t)M * CC;
    unsigned short* wvb   = Vtp   + (size_t)M * CC;
    float*          kbias = (float*)(wvb + (size_t)M * CC);

    dim3 blk(256);

    // 0) fused prep: x->bf16, W_qkv^T, W_out^T, kbias
    prep<<<dim3(CAST_BLOCKS + TQKV_BLOCKS + TOUT_BLOCKS + KB_BLOCKS), blk, 0, stream>>>(
        x, Wqkv, Wout, amask, xb, Wqkvt, Woutt, kbias);

    // 1) QKV projection -> Qp (scaled by 0.125*log2e), Kp packed, Vtp transposed
    gemm_bt_mfma<true><<<dim3(C3 / 128, M / 128), blk, 0, stream>>>(
        xb, Wqkvt, bqkv, nullptr, Qp, Kp, Vtp, M, C3, CC, 0.18033688011112043f);
    // 2) attention: 512 blocks (64 bh x 8 q-tiles of 256 rows, big-first,
    //    XCD-grouped), 512 threads
    attn_mfma<<<dim3(512), dim3(512), 0, stream>>>(
        Qp, Kp, Vtp, kbias, wvb);
    // 3) Output projection (fp32 out)
    gemm_bt_mfma<false><<<dim3(CC / 128, M / 128), blk, 0, stream>>>(
        wvb, Woutt, bout, out, nullptr, nullptr, nullptr, M, CC, CC, 1.0f);
}

// Round 9
// 229.592 us; speedup vs baseline: 1.2563x; 1.2563x over previous
//
#include <hip/hip_runtime.h>
#include <math.h>

// Problem constants (fixed by reference)
constexpr int BB = 4;
constexpr int TT = 2048;
constexpr int CC = 1024;
constexpr int NHH = 16;
constexpr int HDD = 64;    // head dim
constexpr int C3 = 3 * CC; // 3072

typedef __bf16 bf16x8 __attribute__((ext_vector_type(8)));
typedef __bf16 bf16x4 __attribute__((ext_vector_type(4)));
typedef float  f32x4  __attribute__((ext_vector_type(4)));

__device__ __forceinline__ unsigned short f2bf(float x) {
    union { float f; unsigned u; } v; v.f = x;
    unsigned r = v.u + 0x7fffu + ((v.u >> 16) & 1u);  // RNE
    return (unsigned short)(r >> 16);
}

#define AS1(p) ((const __attribute__((address_space(1))) void*)(p))
#define AS3(p) ((__attribute__((address_space(3))) void*)(p))

constexpr float SM2 = 17.312340490667561f;    // 12 * log2(e)

// ---------------------------------------------------------------------------
// prep: (a) x fp32->bf16 cast, (b) W_qkv transpose+cast, (c) W_out
// transpose+cast, (d) kbias = (mask-1)*1e38 - SM2 (fp32) — block-range dispatch.
// ---------------------------------------------------------------------------
constexpr int CAST_BLOCKS = (BB * TT * CC / 4) / 256;          // 8192
constexpr int TQKV_BLOCKS = (C3 / 64) * (CC / 64);             // 768
constexpr int TOUT_BLOCKS = (CC / 64) * (CC / 64);             // 256
constexpr int KB_BLOCKS   = (BB * TT) / 256;                   // 32

__global__ __launch_bounds__(256) void prep(
    const float* __restrict__ x,
    const float* __restrict__ Wqkv,
    const float* __restrict__ Wout,
    const float* __restrict__ amask,
    unsigned short* __restrict__ xb,
    unsigned short* __restrict__ Wqkvt,
    unsigned short* __restrict__ Woutt,
    float* __restrict__ kbias)
{
    __shared__ float tile[64][65];
    const int bid = blockIdx.x;
    const int t = threadIdx.x;

    if (bid < CAST_BLOCKS) {
        const int i = bid * 256 + t;
        float4 v = ((const float4*)x)[i];
        ushort4 o;
        o.x = f2bf(v.x); o.y = f2bf(v.y); o.z = f2bf(v.z); o.w = f2bf(v.w);
        ((ushort4*)xb)[i] = o;
        return;
    }
    if (bid >= CAST_BLOCKS + TQKV_BLOCKS + TOUT_BLOCKS) {
        const int i = (bid - CAST_BLOCKS - TQKV_BLOCKS - TOUT_BLOCKS) * 256 + t;
        kbias[i] = (amask[i] - 1.0f) * 1.0e38f - SM2;
        return;
    }

    const float* src; unsigned short* dst; int R, Cn, r0, c0;
    if (bid < CAST_BLOCKS + TQKV_BLOCKS) {
        const int tb = bid - CAST_BLOCKS;
        src = Wqkv; dst = Wqkvt; R = CC; Cn = C3;
        c0 = (tb % (C3 / 64)) * 64; r0 = (tb / (C3 / 64)) * 64;
    } else {
        const int tb = bid - CAST_BLOCKS - TQKV_BLOCKS;
        src = Wout; dst = Woutt; R = CC; Cn = CC;
        c0 = (tb % (CC / 64)) * 64; r0 = (tb / (CC / 64)) * 64;
    }

    const int lr = t >> 4, lc = (t & 15) * 4;
    #pragma unroll
    for (int s = 0; s < 4; ++s) {
        float4 v = *(const float4*)&src[(size_t)(r0 + lr + s * 16) * Cn + c0 + lc];
        tile[lr + s * 16][lc + 0] = v.x;
        tile[lr + s * 16][lc + 1] = v.y;
        tile[lr + s * 16][lc + 2] = v.z;
        tile[lr + s * 16][lc + 3] = v.w;
    }
    __syncthreads();
    const int oi = t >> 2, oc = (t & 3) * 16;
    unsigned short buf[16];
    #pragma unroll
    for (int u = 0; u < 16; ++u)
        buf[u] = f2bf(tile[oc + u][oi]);
    unsigned short* d = &dst[(size_t)(c0 + oi) * R + r0 + oc];
    *(uint4*)(d + 0) = *(uint4*)&buf[0];
    *(uint4*)(d + 8) = *(uint4*)&buf[8];
}

// ---------------------------------------------------------------------------
// bf16 MFMA GEMM (R5-verified 128x128 structure, both operands via LDS):
// BK=64, XOR-swizzled global_load_lds, counted-vmcnt double-buffer
// (DMA kt+2 after barrier-1, vmcnt(8) across barrier-2), 64KB LDS ->
// 2 blocks/CU. XCD-grouped bijective decode. VSPLIT: Q->Qp scaled,
// K->Kp packed, V->Vtp transposed. Non-VSPLIT: fp32 Out + bias.
// ~92% of its LDS-pipe roofline; R4/R6/R7 proved tile-size moves that
// drop waves/CU regress. Frozen.
// ---------------------------------------------------------------------------
template<bool VSPLIT>
__global__ __launch_bounds__(256, 2) void gemm_bt_mfma(
    const unsigned short* __restrict__ A,   // [M][K]
    const unsigned short* __restrict__ Bt,  // [N][K]
    const float* __restrict__ bias,
    float* __restrict__ OutF,
    unsigned short* __restrict__ Qp,
    unsigned short* __restrict__ Kp,
    unsigned short* __restrict__ Vtp,
    int M, int N, int K, float qscale)
{
    __shared__ alignas(16) unsigned short As[2][128 * 64];  // 32 KB
    __shared__ alignas(16) unsigned short Bs[2][128 * 64];  // 32 KB

    const int tid  = threadIdx.x;
    const int w    = tid >> 6;
    const int lane = tid & 63;
    const int quad = lane >> 4;
    const int col  = lane & 15;

    const int nX  = gridDim.x;
    const int lin = blockIdx.y * nX + blockIdx.x;
    const int pos = lin >> 3;
    const int mt  = ((lin & 7) << 3) | (pos & 7);
    const int nt  = pos >> 3;
    const int m0 = mt * 128, n0 = nt * 128;
    const int wr = w >> 1, wc = w & 1;

    f32x4 acc[4][4];
    #pragma unroll
    for (int i = 0; i < 4; ++i)
        #pragma unroll
        for (int j = 0; j < 4; ++j)
            #pragma unroll
            for (int r = 0; r < 4; ++r)
                acc[i][j][r] = 0.0f;

    const int srow = tid >> 3;   // 0..31
    const int spos = tid & 7;
    char* AsB = (char*)&As[0][0];
    char* BsB = (char*)&Bs[0][0];

    const int nk = K >> 6;

    auto DMA = [&](int kt, int buf) {
        const int k0 = kt << 6;
        #pragma unroll
        for (int i = 0; i < 4; ++i) {
            const int row = srow + 32 * i;
            const int sc = spos ^ (row & 7);
            __builtin_amdgcn_global_load_lds(
                AS1(A + (size_t)(m0 + row) * K + k0 + sc * 8),
                AS3(AsB + buf * 16384 + i * 4096 + w * 1024), 16, 0, 0);
            __builtin_amdgcn_global_load_lds(
                AS1(Bt + (size_t)(n0 + row) * K + k0 + sc * 8),
                AS3(BsB + buf * 16384 + i * 4096 + w * 1024), 16, 0, 0);
        }
    };

    DMA(0, 0);
    DMA(1, 1);
    asm volatile("s_waitcnt vmcnt(8)" ::: "memory");   // tile 0 landed
    __builtin_amdgcn_s_barrier();

    for (int kt = 0; kt < nk; ++kt) {
        const int cur = kt & 1;
        const unsigned short* as = &As[cur][0];
        const unsigned short* bs = &Bs[cur][0];

        #pragma unroll
        for (int ks = 0; ks < 2; ++ks) {
            bf16x8 af[4], bf[4];
            #pragma unroll
            for (int i = 0; i < 4; ++i) {
                const int ra = wr * 64 + i * 16 + col;
                const int pa = ((quad + ks * 4) ^ (ra & 7)) * 8;
                af[i] = *(const bf16x8*)&as[ra * 64 + pa];
                const int rb = wc * 64 + i * 16 + col;
                const int pb = ((quad + ks * 4) ^ (rb & 7)) * 8;
                bf[i] = *(const bf16x8*)&bs[rb * 64 + pb];
            }
            #pragma unroll
            for (int i = 0; i < 4; ++i)
                #pragma unroll
                for (int j = 0; j < 4; ++j)
                    acc[i][j] = __builtin_amdgcn_mfma_f32_16x16x32_bf16(af[i], bf[j], acc[i][j], 0, 0, 0);
        }

        __builtin_amdgcn_s_barrier();
        if (kt + 2 < nk) {
            DMA(kt + 2, cur);
            asm volatile("s_waitcnt vmcnt(8)" ::: "memory");
        } else {
            asm volatile("s_waitcnt vmcnt(0)" ::: "memory");
        }
        __builtin_amdgcn_s_barrier();
    }

    if (VSPLIT) {
        if (n0 < CC) {
            #pragma unroll
            for (int i = 0; i < 4; ++i)
                #pragma unroll
                for (int r = 0; r < 4; ++r) {
                    const int m = m0 + wr * 64 + i * 16 + quad * 4 + r;
                    #pragma unroll
                    for (int j = 0; j < 4; ++j) {
                        const int n = n0 + wc * 64 + j * 16 + col;
                        Qp[(size_t)m * CC + n] = f2bf((acc[i][j][r] + bias[n]) * qscale);
                    }
                }
        } else if (n0 < 2 * CC) {
            #pragma unroll
            for (int i = 0; i < 4; ++i) {
                const int mb   = m0 + wr * 64 + i * 16 + quad * 4;  // + r
                const int bidx = mb >> 11;
                const int tloc = mb & 2047;
                #pragma unroll
                for (int j = 0; j < 4; ++j) {
                    const int n  = n0 + wc * 64 + j * 16 + col;
                    const int hh = (n - CC) >> 6;
                    const int dd = (n - CC) & 63;
                    #pragma unroll
                    for (int r = 0; r < 4; ++r)
                        Kp[(((size_t)bidx * NHH + hh) * TT + tloc + r) * HDD + dd] =
                            f2bf(acc[i][j][r] + bias[n]);
                }
            }
        } else {
            #pragma unroll
            for (int i = 0; i < 4; ++i) {
                const int mb   = m0 + wr * 64 + i * 16 + quad * 4;  // + r
                const int bidx = mb >> 11;
                const int tloc = mb & 2047;
                const int ktile = tloc >> 6, tc = tloc & 63;
                #pragma unroll
                for (int j = 0; j < 4; ++j) {
                    const int n  = n0 + wc * 64 + j * 16 + col;
                    const int hh = (n - 2 * CC) >> 6;
                    const int dd = (n - 2 * CC) & 63;
                    unsigned short pk[4];
                    #pragma unroll
                    for (int r = 0; r < 4; ++r)
                        pk[r] = f2bf(acc[i][j][r] + bias[n]);
                    *(uint2*)&Vtp[((((size_t)bidx * NHH + hh) * 32 + ktile) * HDD + dd) * 64 + tc] =
                        *(const uint2*)pk;
                }
            }
        }
    } else {
        #pragma unroll
        for (int i = 0; i < 4; ++i)
            #pragma unroll
            for (int r = 0; r < 4; ++r) {
                const int m = m0 + wr * 64 + i * 16 + quad * 4 + r;
                #pragma unroll
                for (int j = 0; j < 4; ++j) {
                    const int n = n0 + wc * 64 + j * 16 + col;
                    OutF[(size_t)m * N + n] = acc[i][j][r] + bias[n];
                }
            }
    }
}

// ---------------------------------------------------------------------------
// MFMA flash attention v13 = v11 (R5-verified, ~60us) + two grafts:
//   (a) T5 s_setprio(1) around the QK^T and PV MFMA clusters — waves sit
//       at different phases (3 blocks/CU, per-wave kt<=qw+31 gating), so
//       the CU scheduler has role diversity to arbitrate (+4-7% per guide
//       A/B on attention; null on lockstep GEMMs, so GEMMs untouched).
//   (b) wave-uniform causal-branch hoist — non-edge tiles (~85%) skip the
//       32 per-element cndmasks.
// Everything else byte-identical to v11: swapped QK^T (S^T = mfma(K,Q)),
// P written key-contiguous as ds_write_b64, kbias as MFMA C-init, scalar
// l per lane, 1024 blocks big-qb-first XCD-grouped, counted-vmcnt
// two-barrier pipeline. v12 (256-q/8-wave) regressed 2x — REVERTED
// (conflicts 3x, L2 write churn 6x, co-resident pairing imbalance).
// ---------------------------------------------------------------------------
constexpr int PP = 72;           // Ps row stride (bf16); 144B: 16B-aligned rows

__global__ __launch_bounds__(256, 3) void attn_mfma(
    const unsigned short* __restrict__ Qp,
    const unsigned short* __restrict__ Kp,
    const unsigned short* __restrict__ Vtp,
    const float* __restrict__ kbias,
    unsigned short* __restrict__ WV)
{
    __shared__ alignas(16) unsigned short Ks [2][64 * 64];  // [key][d], swizzled
    __shared__ alignas(16) unsigned short Vts[2][64 * 64];  // [d][tc], swizzled
    __shared__ alignas(16) __bf16        Ps[4][32 * PP];    // per-wave P[q][key]

    const int tid  = threadIdx.x;
    const int w    = tid >> 6;       // 0..3
    const int lane = tid & 63;
    const int quad = lane >> 4;
    const int col  = lane & 15;

    const int gi = blockIdx.x;
    const int j  = gi >> 3;
    const int bh = ((gi & 7) << 3) | (j & 7);
    const int qb = 15 - (j >> 3);
    const int b = bh >> 4, h = bh & 15;

    const unsigned short* Qg = Qp + (size_t)b * TT * CC + (size_t)h * HDD;
    const unsigned short* Kg = Kp + (size_t)bh * TT * HDD;
    const unsigned short* Vg = Vtp + (size_t)bh * 32 * HDD * 64;
    const float* kb_g = kbias + b * TT;

    const int srow = tid >> 3;
    const int sch  = (tid & 7) ^ (srow & 7);
    char* KsB  = (char*)&Ks[0][0];
    char* VtsB = (char*)&Vts[0][0];

    const int qw = qb * 128 + w * 32;   // wave's first q row (32 rows)
    const int ntiles = 2 * qb + 2;      // >= 2

    bf16x8 qfa0 = *(const bf16x8*)(Qg + (size_t)(qw + col) * CC + quad * 8);
    bf16x8 qfa1 = *(const bf16x8*)(Qg + (size_t)(qw + col) * CC + 32 + quad * 8);
    bf16x8 qfb0 = *(const bf16x8*)(Qg + (size_t)(qw + 16 + col) * CC + quad * 8);
    bf16x8 qfb1 = *(const bf16x8*)(Qg + (size_t)(qw + 16 + col) * CC + 32 + quad * 8);

    f32x4 o[2][4];
    float l[2] = {0.0f, 0.0f};
    #pragma unroll
    for (int hh = 0; hh < 2; ++hh)
        #pragma unroll
        for (int t = 0; t < 4; ++t)
            #pragma unroll
            for (int r = 0; r < 4; ++r) o[hh][t][r] = 0.0f;

    auto DMA = [&](int tile, int buf) {
        #pragma unroll
        for (int i = 0; i < 2; ++i) {
            __builtin_amdgcn_global_load_lds(
                AS1(Kg + (size_t)(tile * 64 + srow + 32 * i) * HDD + sch * 8),
                AS3(KsB + buf * 8192 + i * 4096 + w * 1024), 16, 0, 0);
            __builtin_amdgcn_global_load_lds(
                AS1(Vg + ((size_t)tile * 64 + srow + 32 * i) * 64 + sch * 8),
                AS3(VtsB + buf * 8192 + i * 4096 + w * 1024), 16, 0, 0);
        }
    };

    f32x4 kbc[4], kbn[4];
    DMA(0, 0);
    #pragma unroll
    for (int t = 0; t < 4; ++t)
        kbc[t] = *(const f32x4*)&kb_g[t * 16 + quad * 4];
    DMA(1, 1);
    #pragma unroll
    for (int t = 0; t < 4; ++t)
        kbn[t] = *(const f32x4*)&kb_g[64 + t * 16 + quad * 4];
    asm volatile("s_waitcnt vmcnt(8)" ::: "memory");   // tile 0 + kb0 landed
    __builtin_amdgcn_s_barrier();

    for (int it = 0; it < ntiles; ++it) {
        const int kt  = it << 6;
        const int cur = it & 1;

        if (kt <= qw + 31) {  // wave active for this key-tile
            const unsigned short* ksb = &Ks[cur][0];
            const unsigned short* vsb = &Vts[cur][0];

            // --- S^T = K Q^T + kb: lane holds S[q=..+col][key=kt+t*16+quad*4+r]
            f32x4 s[2][4];
            __builtin_amdgcn_s_setprio(1);
            #pragma unroll
            for (int t = 0; t < 4; ++t) {
                const int row = t * 16 + col;
                const int c0 = (quad ^ (row & 7)) * 8;
                const int c1 = ((quad + 4) ^ (row & 7)) * 8;
                bf16x8 k0 = *(const bf16x8*)&ksb[row * 64 + c0];
                bf16x8 k1 = *(const bf16x8*)&ksb[row * 64 + c1];
                f32x4 za = __builtin_amdgcn_mfma_f32_16x16x32_bf16(k0, qfa0, kbc[t], 0, 0, 0);
                za = __builtin_amdgcn_mfma_f32_16x16x32_bf16(k1, qfa1, za, 0, 0, 0);
                s[0][t] = za;
                f32x4 zb = __builtin_amdgcn_mfma_f32_16x16x32_bf16(k0, qfb0, kbc[t], 0, 0, 0);
                zb = __builtin_amdgcn_mfma_f32_16x16x32_bf16(k1, qfb1, zb, 0, 0, 0);
                s[1][t] = zb;
            }
            __builtin_amdgcn_s_setprio(0);

            // --- p = 2^s; causal zero only on wave-edge tiles (uniform) ---
            if (kt + 64 > qw) {
                #pragma unroll
                for (int hh = 0; hh < 2; ++hh) {
                    const int q = qw + hh * 16 + col;
                    #pragma unroll
                    for (int t = 0; t < 4; ++t) {
                        float pv[4];
                        #pragma unroll
                        for (int r = 0; r < 4; ++r) {
                            const int key = kt + t * 16 + quad * 4 + r;
                            float p = __builtin_amdgcn_exp2f(s[hh][t][r]);
                            if (key > q) p = 0.0f;
                            l[hh] += p;
                            pv[r] = p;
                        }
                        bf16x4 pk4 = { (__bf16)pv[0], (__bf16)pv[1],
                                       (__bf16)pv[2], (__bf16)pv[3] };
                        *(bf16x4*)&Ps[w][(hh * 16 + col) * PP + t * 16 + quad * 4] = pk4;
                    }
                }
            } else {
                #pragma unroll
                for (int hh = 0; hh < 2; ++hh) {
                    #pragma unroll
                    for (int t = 0; t < 4; ++t) {
                        float pv[4];
                        #pragma unroll
                        for (int r = 0; r < 4; ++r) {
                            float p = __builtin_amdgcn_exp2f(s[hh][t][r]);
                            l[hh] += p;
                            pv[r] = p;
                        }
                        bf16x4 pk4 = { (__bf16)pv[0], (__bf16)pv[1],
                                       (__bf16)pv[2], (__bf16)pv[3] };
                        *(bf16x4*)&Ps[w][(hh * 16 + col) * PP + t * 16 + quad * 4] = pk4;
                    }
                }
            }

            // --- PV: O += P V; P read back as A-frag (2 b128 per half) ---
            bf16x8 pa0 = *(const bf16x8*)&Ps[w][col * PP + quad * 8];
            bf16x8 pa1 = *(const bf16x8*)&Ps[w][col * PP + 32 + quad * 8];
            bf16x8 pb0 = *(const bf16x8*)&Ps[w][(16 + col) * PP + quad * 8];
            bf16x8 pb1 = *(const bf16x8*)&Ps[w][(16 + col) * PP + 32 + quad * 8];
            __builtin_amdgcn_s_setprio(1);
            #pragma unroll
            for (int t = 0; t < 4; ++t) {
                const int row = t * 16 + col;
                const int c0 = (quad ^ (row & 7)) * 8;
                const int c1 = ((quad + 4) ^ (row & 7)) * 8;
                bf16x8 v0 = *(const bf16x8*)&vsb[row * 64 + c0];
                bf16x8 v1 = *(const bf16x8*)&vsb[row * 64 + c1];
                o[0][t] = __builtin_amdgcn_mfma_f32_16x16x32_bf16(pa0, v0, o[0][t], 0, 0, 0);
                o[0][t] = __builtin_amdgcn_mfma_f32_16x16x32_bf16(pa1, v1, o[0][t], 0, 0, 0);
                o[1][t] = __builtin_amdgcn_mfma_f32_16x16x32_bf16(pb0, v0, o[1][t], 0, 0, 0);
                o[1][t] = __builtin_amdgcn_mfma_f32_16x16x32_bf16(pb1, v1, o[1][t], 0, 0, 0);
            }
            __builtin_amdgcn_s_setprio(0);
        }

        // barrier 1: all waves done READING buf[cur] -> safe to overwrite
        __builtin_amdgcn_s_barrier();

        #pragma unroll
        for (int t = 0; t < 4; ++t) kbc[t] = kbn[t];

        if (it + 2 < ntiles) {
            DMA(it + 2, cur);
            #pragma unroll
            for (int t = 0; t < 4; ++t)
                kbn[t] = *(const f32x4*)&kb_g[(it + 2) * 64 + t * 16 + quad * 4];
            asm volatile("s_waitcnt vmcnt(8)" ::: "memory");
        } else {
            asm volatile("s_waitcnt vmcnt(0)" ::: "memory");
        }
        // barrier 2: buf[(it+1)&1] published to all waves
        __builtin_amdgcn_s_barrier();
    }

    // --- l: reduce across quads (lanes sharing col), broadcast per out-row ---
    #pragma unroll
    for (int hh = 0; hh < 2; ++hh) {
        l[hh] += __shfl_xor(l[hh], 16);
        l[hh] += __shfl_xor(l[hh], 32);
    }
    #pragma unroll
    for (int hh = 0; hh < 2; ++hh) {
        #pragma unroll
        for (int r = 0; r < 4; ++r) {
            const float Lr = __shfl(l[hh], (lane & 48) | (quad * 4 + r));
            const float inv = 1.0f / Lr;
            const int q = qw + hh * 16 + quad * 4 + r;
            unsigned short* dst = WV + ((size_t)b * TT + q) * CC + (size_t)h * HDD;
            #pragma unroll
            for (int t = 0; t < 4; ++t)
                dst[t * 16 + col] = f2bf(o[hh][t][r] * inv);
        }
    }
}

// ---------------------------------------------------------------------------
// Launch
// ---------------------------------------------------------------------------
extern "C" void kernel_launch(void* const* d_in, const int* in_sizes, int n_in,
                              void* d_out, int out_size, void* d_ws, size_t ws_size,
                              hipStream_t stream) {
    const float* x     = (const float*)d_in[0]; // (B,T,C)
    const float* amask = (const float*)d_in[1]; // (B,T)
    const float* Wqkv  = (const float*)d_in[2]; // (C,3C)
    const float* bqkv  = (const float*)d_in[3]; // (3C)
    const float* Wout  = (const float*)d_in[4]; // (C,C)
    const float* bout  = (const float*)d_in[5]; // (C)
    float* out = (float*)d_out;                 // (B,T,C)

    const int M = BB * TT; // 8192

    // Workspace: xb 16M | Wqkvt 6M | Woutt 2M | Qp 16M | Kp 16M | Vtp 16M |
    //            wvb 16M | kbias 32K  (total ~88 MB)
    unsigned short* xb    = (unsigned short*)d_ws;
    unsigned short* Wqkvt = xb    + (size_t)M * CC;
    unsigned short* Woutt = Wqkvt + (size_t)C3 * CC;
    unsigned short* Qp    = Woutt + (size_t)CC * CC;
    unsigned short* Kp    = Qp    + (size_t)M * CC;
    unsigned short* Vtp   = Kp    + (size_t)M * CC;
    unsigned short* wvb   = Vtp   + (size_t)M * CC;
    float*          kbias = (float*)(wvb + (size_t)M * CC);

    dim3 blk(256);

    // 0) fused prep: x->bf16, W_qkv^T, W_out^T, kbias
    prep<<<dim3(CAST_BLOCKS + TQKV_BLOCKS + TOUT_BLOCKS + KB_BLOCKS), blk, 0, stream>>>(
        x, Wqkv, Wout, amask, xb, Wqkvt, Woutt, kbias);

    // 1) QKV projection -> Qp (scaled by 0.125*log2e), Kp packed, Vtp transposed
    gemm_bt_mfma<true><<<dim3(C3 / 128, M / 128), blk, 0, stream>>>(
        xb, Wqkvt, bqkv, nullptr, Qp, Kp, Vtp, M, C3, CC, 0.18033688011112043f);
    // 2) attention: 1024 blocks (bh x 16 q-tiles, big-first, XCD-grouped)
    attn_mfma<<<dim3(1024), dim3(256), 0, stream>>>(
        Qp, Kp, Vtp, kbias, wvb);
    // 3) Output projection (fp32 out)
    gemm_bt_mfma<false><<<dim3(CC / 128, M / 128), blk, 0, stream>>>(
        wvb, Woutt, bout, out, nullptr, nullptr, nullptr, M, CC, CC, 1.0f);
}